// Round 2
// baseline (33001.843 us; speedup 1.0000x reference)
//
#include <hip/hip_runtime.h>
#include <math.h>

// DGCN: diffusion conv (K=2, A_fw==A_bw) + per-node GRU(24 steps) + output proj.
// Strategy:
//   1. csr_build: compact sparse rows of A_fw (~27 nnz/row, cap 96).
//   2. spmm_x:  S1 = A_fw @ X   (X read straight from x with the [B,N,W,F]->[N, B*W*F] view)
//   3. spmm_s:  S2 = A_fw @ S1
//   4. gru_fused: one block per node; computes xin = s0*W0+s1*W1c+s2*W2c on the fly
//      (combined dc weights, since xf==xb duplicates supports), runs all 24 GRU steps
//      with h in LDS (ping-pong), then fuses the W_out projection.
// All fp32 (no fp32 MFMA on CDNA4; this is the correctness baseline).

#define B_ 64
#define N_ 512
#define W_ 24
#define F_ 16
#define H_ 128
#define G3 384
#define XCOLS 24576   // B_*W_*F_
#define XCOLS4 6144   // XCOLS/4
#define CAP 96

__global__ __launch_bounds__(64) void csr_build(const float* __restrict__ A,
                                                int* __restrict__ idx,
                                                float* __restrict__ val,
                                                int* __restrict__ cnt) {
  int n = blockIdx.x;
  int lane = threadIdx.x;
  const float* row = A + (size_t)n * N_;
  int base = 0;
  for (int c = 0; c < N_ / 64; ++c) {
    int m = c * 64 + lane;
    float v = row[m];
    bool p = (v != 0.0f);
    unsigned long long mask = __ballot(p);
    int pos = base + __popcll(mask & ((1ull << lane) - 1ull));
    if (p && pos < CAP) { idx[n * CAP + pos] = m; val[n * CAP + pos] = v; }
    base += __popcll(mask);
  }
  if (lane == 0) cnt[n] = (base < CAP) ? base : CAP;
}

// S1[n][j] = sum_m A[n][m] * X[m][j],  X[m][j] = x[b][m][w][f], j=(b*W+w)*F+f
__global__ __launch_bounds__(256) void spmm_x(const float* __restrict__ x,
                                              const int* __restrict__ idx,
                                              const float* __restrict__ val,
                                              const int* __restrict__ cnt,
                                              float* __restrict__ S1) {
  __shared__ int sm_idx[CAP];
  __shared__ float sm_val[CAP];
  int n = blockIdx.y, jt = blockIdx.x, tid = threadIdx.x;
  int c = cnt[n];
  if (tid < c) { sm_idx[tid] = idx[n * CAP + tid]; sm_val[tid] = val[n * CAP + tid]; }
  __syncthreads();
  int jf = jt * 256 + tid;          // float4 column index, 0..6143
  int b = jf / 96, f4 = jf % 96;    // 96 float4 per b-chunk (W*F/4)
  const float4* xv = (const float4*)x;
  float4 acc = {0.f, 0.f, 0.f, 0.f};
  for (int i = 0; i < c; ++i) {
    int m = sm_idx[i];
    float a = sm_val[i];
    float4 v = xv[((size_t)b * N_ + m) * 96 + f4];
    acc.x += a * v.x; acc.y += a * v.y; acc.z += a * v.z; acc.w += a * v.w;
  }
  ((float4*)S1)[(size_t)n * XCOLS4 + jf] = acc;
}

// S2[n][j] = sum_m A[n][m] * S1[m][j]   (S1 row-major [N][XCOLS])
__global__ __launch_bounds__(256) void spmm_s(const float* __restrict__ S1,
                                              const int* __restrict__ idx,
                                              const float* __restrict__ val,
                                              const int* __restrict__ cnt,
                                              float* __restrict__ S2) {
  __shared__ int sm_idx[CAP];
  __shared__ float sm_val[CAP];
  int n = blockIdx.y, jt = blockIdx.x, tid = threadIdx.x;
  int c = cnt[n];
  if (tid < c) { sm_idx[tid] = idx[n * CAP + tid]; sm_val[tid] = val[n * CAP + tid]; }
  __syncthreads();
  int jf = jt * 256 + tid;
  const float4* sv = (const float4*)S1;
  float4 acc = {0.f, 0.f, 0.f, 0.f};
  for (int i = 0; i < c; ++i) {
    int m = sm_idx[i];
    float a = sm_val[i];
    float4 v = sv[(size_t)m * XCOLS4 + jf];
    acc.x += a * v.x; acc.y += a * v.y; acc.z += a * v.z; acc.w += a * v.w;
  }
  ((float4*)S2)[(size_t)n * XCOLS4 + jf] = acc;
}

__device__ __forceinline__ float dot4(float4 a, float4 b) {
  return a.x * b.x + a.y * b.y + a.z * b.z + a.w * b.w;
}

// One block per node n. 256 threads = 64 b x 4 jl. h kept in LDS across 24 steps.
__global__ __launch_bounds__(256) void gru_fused(
    const float* __restrict__ x, const float* __restrict__ S1,
    const float* __restrict__ S2, const float* __restrict__ dc,
    const float* __restrict__ W_ih, const float* __restrict__ W_hh,
    const float* __restrict__ b_ih, const float* __restrict__ b_hh,
    const float* __restrict__ W_out, const float* __restrict__ b_out,
    float* __restrict__ out) {
  __shared__ __align__(16) float hbuf[2][B_][H_ + 4];   // ping-pong hidden state
  __shared__ __align__(16) float xin_s[B_][H_ + 4];
  __shared__ __align__(16) float sbuf[B_][48];          // s0|s1|s2 slices
  __shared__ __align__(16) float dcw[48][H_];           // combined dc weights

  const int n = blockIdx.x;
  const int tid = threadIdx.x;
  const int b = tid >> 2;
  const int jl = tid & 3;

  // combined diffusion-conv weights: W0 = dc[0:16]; W1c = dc[16:32]+dc[32:48]; W2c = dc[48:64]+dc[64:80]
  for (int k2 = tid; k2 < 48 * H_; k2 += 256) {
    int f = k2 >> 7, j = k2 & 127;
    float v;
    if (f < 16)      v = dc[f * H_ + j];
    else if (f < 32) v = dc[f * H_ + j] + dc[(f + 16) * H_ + j];
    else             v = dc[(f + 16) * H_ + j] + dc[(f + 32) * H_ + j];
    dcw[f][j] = v;
  }
  for (int k2 = tid; k2 < B_ * (H_ + 4); k2 += 256) (&hbuf[0][0][0])[k2] = 0.0f;
  __syncthreads();

  float (*hc)[H_ + 4] = hbuf[0];   // current h
  float (*hx)[H_ + 4] = hbuf[1];   // next h

  const float4* Wi = (const float4*)(W_ih + (size_t)n * G3 * H_);
  const float4* Wh = (const float4*)(W_hh + (size_t)n * G3 * H_);
  const float* bi = b_ih + n * G3;
  const float* bh = b_hh + n * G3;

  for (int t = 0; t < W_; ++t) {
    // ---- stage s0/s1/s2 slices (one float4 per thread per support) ----
    {
      float4 v0 = ((const float4*)x)[(((size_t)b * N_ + n) * W_ + t) * 4 + jl];
      float4 v1 = ((const float4*)S1)[(size_t)n * XCOLS4 + (b * W_ + t) * 4 + jl];
      float4 v2 = ((const float4*)S2)[(size_t)n * XCOLS4 + (b * W_ + t) * 4 + jl];
      *(float4*)&sbuf[b][jl * 4]      = v0;
      *(float4*)&sbuf[b][16 + jl * 4] = v1;
      *(float4*)&sbuf[b][32 + jl * 4] = v2;
    }
    __syncthreads();
    // ---- xin[b][j] = sum_f sbuf[b][f] * dcw[f][j] ----
    {
      float sreg[48];
      #pragma unroll
      for (int f = 0; f < 48; ++f) sreg[f] = sbuf[b][f];
      for (int jo = 0; jo < 32; ++jo) {
        int j = jo * 4 + jl;
        float acc = 0.f;
        #pragma unroll
        for (int f = 0; f < 48; ++f) acc += sreg[f] * dcw[f][j];
        xin_s[b][j] = acc;
      }
    }
    __syncthreads();
    // ---- gates: 6 dot-products of length 128 per output element ----
    {
      const float4* xv4 = (const float4*)&xin_s[b][0];
      const float4* hv4 = (const float4*)&hc[b][0];
      for (int jo = 0; jo < 32; ++jo) {
        int j = jo * 4 + jl;
        float ir = bi[j], iz = bi[H_ + j], in_ = bi[2 * H_ + j];
        float hr = bh[j], hz = bh[H_ + j], hn = bh[2 * H_ + j];
        const float4* wir = Wi + (size_t)j * 32;
        const float4* wiz = Wi + (size_t)(H_ + j) * 32;
        const float4* win = Wi + (size_t)(2 * H_ + j) * 32;
        const float4* whr = Wh + (size_t)j * 32;
        const float4* whz = Wh + (size_t)(H_ + j) * 32;
        const float4* whn = Wh + (size_t)(2 * H_ + j) * 32;
        #pragma unroll 8
        for (int k = 0; k < 32; ++k) {
          float4 xv = xv4[k], hv = hv4[k];
          ir  += dot4(xv, wir[k]);
          iz  += dot4(xv, wiz[k]);
          in_ += dot4(xv, win[k]);
          hr  += dot4(hv, whr[k]);
          hz  += dot4(hv, whz[k]);
          hn  += dot4(hv, whn[k]);
        }
        float r = 1.f / (1.f + __expf(-(ir + hr)));
        float z = 1.f / (1.f + __expf(-(iz + hz)));
        float av = in_ + r * hn;
        float e2 = __expf(-2.f * fabsf(av));
        float th = (1.f - e2) / (1.f + e2);
        th = copysignf(th, av);
        hx[b][j] = (1.f - z) * th + z * hc[b][j];
      }
    }
    // swap ping-pong (no barrier needed here: next write targets sbuf, which is
    // only re-read after the post-stage barrier; xin_s rewritten after that too)
    float (*tmp)[H_ + 4] = hc; hc = hx; hx = tmp;
    __syncthreads();
  }
  // ---- output projection: out[b][n][f] = h . W_out[:,f] + b_out ----
  {
    float4 acc = ((const float4*)b_out)[jl];
    for (int hh = 0; hh < H_; ++hh) {
      float hv = hc[b][hh];
      float4 w = ((const float4*)W_out)[hh * 4 + jl];
      acc.x += hv * w.x; acc.y += hv * w.y; acc.z += hv * w.z; acc.w += hv * w.w;
    }
    ((float4*)out)[((size_t)b * N_ + n) * 4 + jl] = acc;
  }
}

extern "C" void kernel_launch(void* const* d_in, const int* in_sizes, int n_in,
                              void* d_out, int out_size, void* d_ws, size_t ws_size,
                              hipStream_t stream) {
  const float* x     = (const float*)d_in[0];
  const float* A_fw  = (const float*)d_in[1];
  const float* dc    = (const float*)d_in[2];
  const float* W_ih  = (const float*)d_in[3];
  const float* W_hh  = (const float*)d_in[4];
  const float* b_ih  = (const float*)d_in[5];
  const float* b_hh  = (const float*)d_in[6];
  const float* W_out = (const float*)d_in[7];
  const float* b_out = (const float*)d_in[8];
  float* out = (float*)d_out;

  // workspace layout
  float* S1  = (float*)d_ws;                      // 512*24576 floats
  float* S2  = S1 + (size_t)N_ * XCOLS;           // 512*24576 floats
  float* val = S2 + (size_t)N_ * XCOLS;           // 512*96
  int*   idx = (int*)(val + N_ * CAP);            // 512*96
  int*   cnt = idx + N_ * CAP;                    // 512

  csr_build<<<dim3(N_), dim3(64), 0, stream>>>(A_fw, idx, val, cnt);
  dim3 gs(XCOLS4 / 256, N_);
  spmm_x<<<gs, dim3(256), 0, stream>>>(x, idx, val, cnt, S1);
  spmm_s<<<gs, dim3(256), 0, stream>>>(S1, idx, val, cnt, S2);
  gru_fused<<<dim3(N_), dim3(256), 0, stream>>>(x, S1, S2, dc, W_ih, W_hh,
                                                b_ih, b_hh, W_out, b_out, out);
}

// Round 3
// 673.863 us; speedup vs baseline: 48.9741x; 48.9741x over previous
//
#include <hip/hip_runtime.h>
#include <math.h>

// DGCN on MI355X, MFMA version.
// gi = s @ (dcw @ W_ih^T)  [K=48->64 padded, bf16 MFMA]
// gh = h @ W_hh^T          [K=128, bf16 MFMA, B-frags register-resident all 24 steps]
// h lives in LDS (bf16); wave w owns hidden-tile w and gate tiles {w, w+8, w+16}
// so the r/z/n combine is lane-local (C/D layout: col=lane&15, row=(lane>>4)*4+reg).

#define B_ 64
#define N_ 512
#define W_ 24
#define F_ 16
#define H_ 128
#define G3 384
#define XCOLS 24576   // B*W*F
#define XCOLS4 6144
#define CAP 96
#define PAD_S 72      // s_tile row stride (ushorts): 144B = 9*16B, 2-way-bank-conflict only
#define PAD_H 136     // h_tile row stride: 272B = 17*16B

typedef __attribute__((ext_vector_type(8))) short short8;
typedef __attribute__((ext_vector_type(4))) float f32x4;

__device__ __forceinline__ unsigned short f2bf(float f) {
  unsigned int u = __float_as_uint(f);
  u += 0x7FFFu + ((u >> 16) & 1u);
  return (unsigned short)(u >> 16);
}
__device__ __forceinline__ float bf2f(unsigned short s) {
  return __uint_as_float(((unsigned int)s) << 16);
}

// ---------------- CSR of A_fw (~27 nnz/row) ----------------
__global__ __launch_bounds__(64) void csr_build(const float* __restrict__ A,
                                                int* __restrict__ idx,
                                                float* __restrict__ val,
                                                int* __restrict__ cnt) {
  int n = blockIdx.x;
  int lane = threadIdx.x;
  const float* row = A + (size_t)n * N_;
  int base = 0;
  for (int c = 0; c < N_ / 64; ++c) {
    int m = c * 64 + lane;
    float v = row[m];
    bool p = (v != 0.0f);
    unsigned long long mask = __ballot(p);
    int pos = base + __popcll(mask & ((1ull << lane) - 1ull));
    if (p && pos < CAP) { idx[n * CAP + pos] = m; val[n * CAP + pos] = v; }
    base += __popcll(mask);
  }
  if (lane == 0) cnt[n] = (base < CAP) ? base : CAP;
}

// ---------------- combined dc weights: dcw[48][128] ----------------
__global__ __launch_bounds__(256) void dcw_build(const float* __restrict__ dc,
                                                 float* __restrict__ dcw) {
  for (int i = threadIdx.x; i < 48 * H_; i += 256) {
    int f = i >> 7, j = i & 127;
    float v;
    if (f < 16)      v = dc[f * H_ + j];
    else if (f < 32) v = dc[f * H_ + j] + dc[(f + 16) * H_ + j];
    else             v = dc[(f + 16) * H_ + j] + dc[(f + 32) * H_ + j];
    dcw[i] = v;
  }
}

// ---------------- S1 = A @ X (bf16 out) ----------------
__global__ __launch_bounds__(256) void spmm_x(const float* __restrict__ x,
                                              const int* __restrict__ idx,
                                              const float* __restrict__ val,
                                              const int* __restrict__ cnt,
                                              unsigned short* __restrict__ S1) {
  __shared__ int sm_idx[CAP];
  __shared__ float sm_val[CAP];
  int n = blockIdx.y, jt = blockIdx.x, tid = threadIdx.x;
  int c = cnt[n];
  if (tid < c) { sm_idx[tid] = idx[n * CAP + tid]; sm_val[tid] = val[n * CAP + tid]; }
  __syncthreads();
  int jf = jt * 256 + tid;          // 4-col group, 0..6143
  int b = jf / 96, f4 = jf % 96;
  const float4* xv = (const float4*)x;
  float4 acc = {0.f, 0.f, 0.f, 0.f};
  for (int i = 0; i < c; ++i) {
    int m = sm_idx[i];
    float a = sm_val[i];
    float4 v = xv[((size_t)b * N_ + m) * 96 + f4];
    acc.x += a * v.x; acc.y += a * v.y; acc.z += a * v.z; acc.w += a * v.w;
  }
  ushort4 o = {f2bf(acc.x), f2bf(acc.y), f2bf(acc.z), f2bf(acc.w)};
  ((ushort4*)S1)[(size_t)n * XCOLS4 + jf] = o;
}

// ---------------- S2 = A @ S1 (bf16 in/out) ----------------
__global__ __launch_bounds__(256) void spmm_s(const unsigned short* __restrict__ S1,
                                              const int* __restrict__ idx,
                                              const float* __restrict__ val,
                                              const int* __restrict__ cnt,
                                              unsigned short* __restrict__ S2) {
  __shared__ int sm_idx[CAP];
  __shared__ float sm_val[CAP];
  int n = blockIdx.y, jt = blockIdx.x, tid = threadIdx.x;
  int c = cnt[n];
  if (tid < c) { sm_idx[tid] = idx[n * CAP + tid]; sm_val[tid] = val[n * CAP + tid]; }
  __syncthreads();
  int jf = jt * 256 + tid;
  float4 acc = {0.f, 0.f, 0.f, 0.f};
  for (int i = 0; i < c; ++i) {
    int m = sm_idx[i];
    float a = sm_val[i];
    ushort4 v = ((const ushort4*)S1)[(size_t)m * XCOLS4 + jf];
    acc.x += a * bf2f(v.x); acc.y += a * bf2f(v.y);
    acc.z += a * bf2f(v.z); acc.w += a * bf2f(v.w);
  }
  ushort4 o = {f2bf(acc.x), f2bf(acc.y), f2bf(acc.z), f2bf(acc.w)};
  ((ushort4*)S2)[(size_t)n * XCOLS4 + jf] = o;
}

// ---------------- M_i[n][g][f64] = (dcw @ W_ih[n]^T)^T, bf16, f rows padded to 64 ----------------
__global__ __launch_bounds__(384) void prep_mi(const float* __restrict__ dcw,
                                               const float* __restrict__ W_ih,
                                               unsigned short* __restrict__ Mi) {
  __shared__ float dl[48 * H_];
  int n = blockIdx.x, tid = threadIdx.x;
  for (int i = tid; i < 48 * H_; i += 384) dl[i] = dcw[i];
  __syncthreads();
  int g = tid;   // 0..383
  float acc[48];
  #pragma unroll
  for (int f = 0; f < 48; ++f) acc[f] = 0.f;
  const float* wr = W_ih + ((size_t)n * G3 + g) * H_;
  for (int hc = 0; hc < 8; ++hc) {
    float wl[16];
    const float4* wp = (const float4*)(wr + hc * 16);
    float4 w0 = wp[0], w1 = wp[1], w2 = wp[2], w3 = wp[3];
    wl[0]=w0.x; wl[1]=w0.y; wl[2]=w0.z; wl[3]=w0.w;
    wl[4]=w1.x; wl[5]=w1.y; wl[6]=w1.z; wl[7]=w1.w;
    wl[8]=w2.x; wl[9]=w2.y; wl[10]=w2.z; wl[11]=w2.w;
    wl[12]=w3.x; wl[13]=w3.y; wl[14]=w3.z; wl[15]=w3.w;
    for (int f = 0; f < 48; ++f) {
      const float* dr = &dl[f * H_ + hc * 16];
      float a = acc[f];
      #pragma unroll
      for (int i = 0; i < 16; ++i) a += dr[i] * wl[i];
      acc[f] = a;
    }
  }
  unsigned short* dst = Mi + ((size_t)n * G3 + g) * 64;
  #pragma unroll
  for (int f = 0; f < 48; ++f) dst[f] = f2bf(acc[f]);
  #pragma unroll
  for (int f = 48; f < 64; ++f) dst[f] = 0;
}

// ---------------- fused GRU: 1 block/node, 8 waves, 24 steps ----------------
__global__ __launch_bounds__(512) void gru_mfma(
    const float* __restrict__ x, const unsigned short* __restrict__ S1,
    const unsigned short* __restrict__ S2, const unsigned short* __restrict__ Mi,
    const float* __restrict__ W_hh, const float* __restrict__ b_ih,
    const float* __restrict__ b_hh, const float* __restrict__ W_out,
    const float* __restrict__ b_out, float* __restrict__ out) {
  __shared__ __align__(16) unsigned short s_lds[B_ * PAD_S];
  __shared__ __align__(16) unsigned short h_lds[B_ * PAD_H];
  __shared__ float wout_lds[H_ * F_];

  const int n = blockIdx.x;
  const int tid = threadIdx.x;
  const int w = tid >> 6;        // wave 0..7 = hidden tile
  const int l = tid & 63;
  const int l15 = l & 15;
  const int lhi = l >> 4;        // 0..3

  for (int i = tid; i < B_ * PAD_H; i += 512) h_lds[i] = 0;
  for (int i = tid; i < H_ * F_; i += 512) wout_lds[i] = W_out[i];

  // register-resident B-fragments (all 24 steps): W_hh (fp32->bf16) and M_i
  short8 whf[3][4];
  short8 mif[3][2];
  float bi3[3], bh3[3];
  const float* whh_n = W_hh + (size_t)n * G3 * H_;
  const unsigned short* mi_n = Mi + (size_t)n * G3 * 64;
  #pragma unroll
  for (int ntl = 0; ntl < 3; ++ntl) {
    const int g = (ntl * 8 + w) * 16 + l15;   // gate ntl, hidden tile w
    #pragma unroll
    for (int ks = 0; ks < 4; ++ks) {
      const float4* p = (const float4*)(whh_n + (size_t)g * H_ + ks * 32 + lhi * 8);
      float4 a = p[0], b2 = p[1];
      short8 r;
      r[0]=(short)f2bf(a.x); r[1]=(short)f2bf(a.y); r[2]=(short)f2bf(a.z); r[3]=(short)f2bf(a.w);
      r[4]=(short)f2bf(b2.x); r[5]=(short)f2bf(b2.y); r[6]=(short)f2bf(b2.z); r[7]=(short)f2bf(b2.w);
      whf[ntl][ks] = r;
    }
    #pragma unroll
    for (int ks = 0; ks < 2; ++ks)
      mif[ntl][ks] = *(const short8*)(mi_n + (size_t)g * 64 + ks * 32 + lhi * 8);
    bi3[ntl] = b_ih[n * G3 + g];
    bh3[ntl] = b_hh[n * G3 + g];
  }

  for (int t = 0; t < W_; ++t) {
    // ---- stage s_t[64 b][64 f] bf16: f 0..15 x | 16..31 S1 | 32..47 S2 | 48..63 zero
    {
      const int brow = tid >> 3, seg = tid & 7;
      ushort4 lo, hi;
      if (seg < 2) {
        const float4* xp = (const float4*)x + (((size_t)brow * N_ + n) * W_ + t) * 4 + seg * 2;
        float4 a = xp[0], b2 = xp[1];
        lo = (ushort4){f2bf(a.x), f2bf(a.y), f2bf(a.z), f2bf(a.w)};
        hi = (ushort4){f2bf(b2.x), f2bf(b2.y), f2bf(b2.z), f2bf(b2.w)};
      } else if (seg < 6) {
        const unsigned short* src = (seg < 4) ? S1 : S2;
        const ushort4* p = (const ushort4*)(src + (size_t)n * XCOLS + (brow * W_ + t) * F_ + (seg & 1) * 8);
        lo = p[0]; hi = p[1];
      } else {
        lo = (ushort4){0,0,0,0}; hi = lo;
      }
      *(ushort4*)&s_lds[brow * PAD_S + seg * 8] = lo;
      *(ushort4*)&s_lds[brow * PAD_S + seg * 8 + 4] = hi;
    }
    __syncthreads();

    // ---- MFMA phase: gi (K=64) + gh (K=128)
    f32x4 acc_i[4][3], acc_h[4][3];
    #pragma unroll
    for (int mt = 0; mt < 4; ++mt)
      #pragma unroll
      for (int ntl = 0; ntl < 3; ++ntl) {
        acc_i[mt][ntl] = (f32x4){bi3[ntl], bi3[ntl], bi3[ntl], bi3[ntl]};
        acc_h[mt][ntl] = (f32x4){bh3[ntl], bh3[ntl], bh3[ntl], bh3[ntl]};
      }
    #pragma unroll
    for (int mt = 0; mt < 4; ++mt) {
      const int arow = mt * 16 + l15;
      short8 as0 = *(const short8*)&s_lds[arow * PAD_S + lhi * 8];
      short8 as1 = *(const short8*)&s_lds[arow * PAD_S + 32 + lhi * 8];
      short8 ah0 = *(const short8*)&h_lds[arow * PAD_H + lhi * 8];
      short8 ah1 = *(const short8*)&h_lds[arow * PAD_H + 32 + lhi * 8];
      short8 ah2 = *(const short8*)&h_lds[arow * PAD_H + 64 + lhi * 8];
      short8 ah3 = *(const short8*)&h_lds[arow * PAD_H + 96 + lhi * 8];
      #pragma unroll
      for (int ntl = 0; ntl < 3; ++ntl) {
        acc_i[mt][ntl] = __builtin_amdgcn_mfma_f32_16x16x32_bf16(as0, mif[ntl][0], acc_i[mt][ntl], 0, 0, 0);
        acc_i[mt][ntl] = __builtin_amdgcn_mfma_f32_16x16x32_bf16(as1, mif[ntl][1], acc_i[mt][ntl], 0, 0, 0);
        acc_h[mt][ntl] = __builtin_amdgcn_mfma_f32_16x16x32_bf16(ah0, whf[ntl][0], acc_h[mt][ntl], 0, 0, 0);
        acc_h[mt][ntl] = __builtin_amdgcn_mfma_f32_16x16x32_bf16(ah1, whf[ntl][1], acc_h[mt][ntl], 0, 0, 0);
        acc_h[mt][ntl] = __builtin_amdgcn_mfma_f32_16x16x32_bf16(ah2, whf[ntl][2], acc_h[mt][ntl], 0, 0, 0);
        acc_h[mt][ntl] = __builtin_amdgcn_mfma_f32_16x16x32_bf16(ah3, whf[ntl][3], acc_h[mt][ntl], 0, 0, 0);
      }
    }
    __syncthreads();

    // ---- elementwise gate combine (lane-local) + h update
    const int hcol = w * 16 + l15;
    #pragma unroll
    for (int mt = 0; mt < 4; ++mt) {
      #pragma unroll
      for (int r = 0; r < 4; ++r) {
        const int brow = mt * 16 + lhi * 4 + r;
        float rg = 1.f / (1.f + __expf(-(acc_i[mt][0][r] + acc_h[mt][0][r])));
        float zg = 1.f / (1.f + __expf(-(acc_i[mt][1][r] + acc_h[mt][1][r])));
        float av = acc_i[mt][2][r] + rg * acc_h[mt][2][r];
        float e2 = __expf(-2.f * fabsf(av));
        float th = (1.f - e2) / (1.f + e2);
        th = copysignf(th, av);
        float hp = bf2f(h_lds[brow * PAD_H + hcol]);
        float hnew = (1.f - zg) * th + zg * hp;
        h_lds[brow * PAD_H + hcol] = f2bf(hnew);
      }
    }
    // loop-top barrier (after stage) orders these writes vs next MFMA reads
  }
  __syncthreads();

  // ---- output projection out[b][n][f] = h . W_out[:,f] + b_out[f]
  for (int e = tid; e < B_ * F_; e += 512) {
    const int b = e >> 4, f = e & 15;
    float a = b_out[f];
    for (int h = 0; h < H_; ++h)
      a += bf2f(h_lds[b * PAD_H + h]) * wout_lds[h * F_ + f];
    out[((size_t)b * N_ + n) * F_ + f] = a;
  }
}

extern "C" void kernel_launch(void* const* d_in, const int* in_sizes, int n_in,
                              void* d_out, int out_size, void* d_ws, size_t ws_size,
                              hipStream_t stream) {
  const float* x     = (const float*)d_in[0];
  const float* A_fw  = (const float*)d_in[1];
  const float* dc    = (const float*)d_in[2];
  const float* W_ih  = (const float*)d_in[3];
  const float* W_hh  = (const float*)d_in[4];
  const float* b_ih  = (const float*)d_in[5];
  const float* b_hh  = (const float*)d_in[6];
  const float* W_out = (const float*)d_in[7];
  const float* b_out = (const float*)d_in[8];
  float* out = (float*)d_out;

  // workspace layout (~76 MB)
  unsigned short* S1 = (unsigned short*)d_ws;              // 512*24576 bf16
  unsigned short* S2 = S1 + (size_t)N_ * XCOLS;            // 512*24576 bf16
  unsigned short* Mi = S2 + (size_t)N_ * XCOLS;            // 512*384*64 bf16
  float* dcw = (float*)(Mi + (size_t)N_ * G3 * 64);        // 48*128 f32
  float* val = dcw + 48 * H_;                              // 512*96
  int*   idx = (int*)(val + N_ * CAP);
  int*   cnt = idx + N_ * CAP;

  csr_build<<<dim3(N_), dim3(64), 0, stream>>>(A_fw, idx, val, cnt);
  dcw_build<<<dim3(1), dim3(256), 0, stream>>>(dc, dcw);
  dim3 gs(XCOLS4 / 256, N_);
  spmm_x<<<gs, dim3(256), 0, stream>>>(x, idx, val, cnt, S1);
  spmm_s<<<gs, dim3(256), 0, stream>>>(S1, idx, val, cnt, S2);
  prep_mi<<<dim3(N_), dim3(384), 0, stream>>>(dcw, W_ih, Mi);
  gru_mfma<<<dim3(N_), dim3(512), 0, stream>>>(x, S1, S2, Mi, W_hh, b_ih, b_hh,
                                               W_out, b_out, out);
}

// Round 4
// 622.946 us; speedup vs baseline: 52.9770x; 1.0817x over previous
//
#include <hip/hip_runtime.h>
#include <math.h>

// DGCN on MI355X, MFMA v2 (operand-swapped GRU).
// gi^T = Mi(A) @ s(B), gh^T = W_hh(A) @ h(B)  [bf16 MFMA 16x16x32]
// D layout: col=lane&15=batch, row=(lane>>4)*4+r = hidden-within-tile -> per-lane
// 4 consecutive hidden values => packed ushort4 h-writes (no scalar LDS transpose).
// s/h tiles XOR-swizzled (slot ^= row&7), double-buffered, 1 barrier/step.

#define B_ 64
#define N_ 512
#define W_ 24
#define F_ 16
#define H_ 128
#define G3 384
#define XCOLS 24576   // B*W*F
#define XCOLS4 6144
#define CAP 96

typedef __attribute__((ext_vector_type(8))) short short8;
typedef __attribute__((ext_vector_type(4))) float f32x4;
#define MFMA __builtin_amdgcn_mfma_f32_16x16x32_bf16

__device__ __forceinline__ unsigned short f2bf(float f) {
  unsigned int u = __float_as_uint(f);
  u += 0x7FFFu + ((u >> 16) & 1u);
  return (unsigned short)(u >> 16);
}
__device__ __forceinline__ float bf2f(unsigned short s) {
  return __uint_as_float(((unsigned int)s) << 16);
}

// ---------------- x -> bf16 (also feeds gru staging as pure copies) ----------------
__global__ __launch_bounds__(256) void xbf_conv(const float* __restrict__ x,
                                                unsigned short* __restrict__ xbf) {
  size_t i = ((size_t)blockIdx.x * 256 + threadIdx.x) * 8;
  const float4* p = (const float4*)(x + i);
  float4 a = p[0], b = p[1];
  short8 o;
  o[0]=(short)f2bf(a.x); o[1]=(short)f2bf(a.y); o[2]=(short)f2bf(a.z); o[3]=(short)f2bf(a.w);
  o[4]=(short)f2bf(b.x); o[5]=(short)f2bf(b.y); o[6]=(short)f2bf(b.z); o[7]=(short)f2bf(b.w);
  *(short8*)(xbf + i) = o;
}

// ---------------- CSR of A_fw (~27 nnz/row) ----------------
__global__ __launch_bounds__(64) void csr_build(const float* __restrict__ A,
                                                int* __restrict__ idx,
                                                float* __restrict__ val,
                                                int* __restrict__ cnt) {
  int n = blockIdx.x;
  int lane = threadIdx.x;
  const float* row = A + (size_t)n * N_;
  int base = 0;
  for (int c = 0; c < N_ / 64; ++c) {
    int m = c * 64 + lane;
    float v = row[m];
    bool p = (v != 0.0f);
    unsigned long long mask = __ballot(p);
    int pos = base + __popcll(mask & ((1ull << lane) - 1ull));
    if (p && pos < CAP) { idx[n * CAP + pos] = m; val[n * CAP + pos] = v; }
    base += __popcll(mask);
  }
  if (lane == 0) cnt[n] = (base < CAP) ? base : CAP;
}

// ---------------- combined dc weights: dcw[48][128] ----------------
__global__ __launch_bounds__(256) void dcw_build(const float* __restrict__ dc,
                                                 float* __restrict__ dcw) {
  for (int i = threadIdx.x; i < 48 * H_; i += 256) {
    int f = i >> 7, j = i & 127;
    float v;
    if (f < 16)      v = dc[f * H_ + j];
    else if (f < 32) v = dc[f * H_ + j] + dc[(f + 16) * H_ + j];
    else             v = dc[(f + 16) * H_ + j] + dc[(f + 32) * H_ + j];
    dcw[i] = v;
  }
}

// ---------------- S1 = A @ X (bf16 in/out) ----------------
__global__ __launch_bounds__(256) void spmm_x(const unsigned short* __restrict__ xbf,
                                              const int* __restrict__ idx,
                                              const float* __restrict__ val,
                                              const int* __restrict__ cnt,
                                              unsigned short* __restrict__ S1) {
  __shared__ int sm_idx[CAP];
  __shared__ float sm_val[CAP];
  int n = blockIdx.y, jt = blockIdx.x, tid = threadIdx.x;
  int c = cnt[n];
  if (tid < c) { sm_idx[tid] = idx[n * CAP + tid]; sm_val[tid] = val[n * CAP + tid]; }
  __syncthreads();
  int jf = jt * 256 + tid;          // ushort4 col group, 0..6143
  int b = jf / 96, f4 = jf % 96;
  float4 acc = {0.f, 0.f, 0.f, 0.f};
  for (int i = 0; i < c; ++i) {
    int m = sm_idx[i];
    float a = sm_val[i];
    ushort4 v = ((const ushort4*)xbf)[((size_t)b * N_ + m) * 96 + f4];
    acc.x += a * bf2f(v.x); acc.y += a * bf2f(v.y);
    acc.z += a * bf2f(v.z); acc.w += a * bf2f(v.w);
  }
  ushort4 o = {f2bf(acc.x), f2bf(acc.y), f2bf(acc.z), f2bf(acc.w)};
  ((ushort4*)S1)[(size_t)n * XCOLS4 + jf] = o;
}

// ---------------- S2 = A @ S1 (bf16 in/out) ----------------
__global__ __launch_bounds__(256) void spmm_s(const unsigned short* __restrict__ S1,
                                              const int* __restrict__ idx,
                                              const float* __restrict__ val,
                                              const int* __restrict__ cnt,
                                              unsigned short* __restrict__ S2) {
  __shared__ int sm_idx[CAP];
  __shared__ float sm_val[CAP];
  int n = blockIdx.y, jt = blockIdx.x, tid = threadIdx.x;
  int c = cnt[n];
  if (tid < c) { sm_idx[tid] = idx[n * CAP + tid]; sm_val[tid] = val[n * CAP + tid]; }
  __syncthreads();
  int jf = jt * 256 + tid;
  float4 acc = {0.f, 0.f, 0.f, 0.f};
  for (int i = 0; i < c; ++i) {
    int m = sm_idx[i];
    float a = sm_val[i];
    ushort4 v = ((const ushort4*)S1)[(size_t)m * XCOLS4 + jf];
    acc.x += a * bf2f(v.x); acc.y += a * bf2f(v.y);
    acc.z += a * bf2f(v.z); acc.w += a * bf2f(v.w);
  }
  ushort4 o = {f2bf(acc.x), f2bf(acc.y), f2bf(acc.z), f2bf(acc.w)};
  ((ushort4*)S2)[(size_t)n * XCOLS4 + jf] = o;
}

// ---------------- M_i[n][g][f64] = (dcw @ W_ih[n]^T)^T, bf16, padded to 64 ----------------
__global__ __launch_bounds__(384) void prep_mi(const float* __restrict__ dcw,
                                               const float* __restrict__ W_ih,
                                               unsigned short* __restrict__ Mi) {
  __shared__ float dl[48 * H_];
  int n = blockIdx.x, tid = threadIdx.x;
  for (int i = tid; i < 48 * H_; i += 384) dl[i] = dcw[i];
  __syncthreads();
  int g = tid;
  float acc[48];
  #pragma unroll
  for (int f = 0; f < 48; ++f) acc[f] = 0.f;
  const float* wr = W_ih + ((size_t)n * G3 + g) * H_;
  for (int hc = 0; hc < 8; ++hc) {
    float wl[16];
    const float4* wp = (const float4*)(wr + hc * 16);
    float4 w0 = wp[0], w1 = wp[1], w2 = wp[2], w3 = wp[3];
    wl[0]=w0.x; wl[1]=w0.y; wl[2]=w0.z; wl[3]=w0.w;
    wl[4]=w1.x; wl[5]=w1.y; wl[6]=w1.z; wl[7]=w1.w;
    wl[8]=w2.x; wl[9]=w2.y; wl[10]=w2.z; wl[11]=w2.w;
    wl[12]=w3.x; wl[13]=w3.y; wl[14]=w3.z; wl[15]=w3.w;
    for (int f = 0; f < 48; ++f) {
      const float* dr = &dl[f * H_ + hc * 16];
      float a = acc[f];
      #pragma unroll
      for (int i = 0; i < 16; ++i) a += dr[i] * wl[i];
      acc[f] = a;
    }
  }
  unsigned short* dst = Mi + ((size_t)n * G3 + g) * 64;
  #pragma unroll
  for (int f = 0; f < 48; ++f) dst[f] = f2bf(acc[f]);
  #pragma unroll
  for (int f = 48; f < 64; ++f) dst[f] = 0;
}

// ---------------- fused GRU v2: 1 block/node, 8 waves, operand-swapped ----------------
__global__ __launch_bounds__(512) void gru_mfma(
    const unsigned short* __restrict__ xbf, const unsigned short* __restrict__ S1,
    const unsigned short* __restrict__ S2, const unsigned short* __restrict__ Mi,
    const float* __restrict__ W_hh, const float* __restrict__ b_ih,
    const float* __restrict__ b_hh, const float* __restrict__ W_out,
    const float* __restrict__ b_out, float* __restrict__ out) {
  __shared__ __align__(16) unsigned short s_lds[2][B_ * 64];    // row=128B, swizzled
  __shared__ __align__(16) unsigned short h_lds[2][B_ * H_];    // row=256B, swizzled
  __shared__ __align__(16) float wout_lds[H_ * F_];

  const int n = blockIdx.x;
  const int tid = threadIdx.x;
  const int w = tid >> 6;        // wave = hidden tile (16 cols each)
  const int l = tid & 63;
  const int l15 = l & 15;
  const int lhi = l >> 4;        // 0..3
  const int brow = tid >> 3, seg = tid & 7;

  // init: h[0]=0; zero-pad slots 6,7 of both s buffers; stage W_out
  for (int i = tid; i < B_ * H_; i += 512) h_lds[0][i] = 0;
  if (tid < 256) {
    int buf = tid >> 7, row = (tid >> 1) & 63, sg = 6 + (tid & 1);
    *(short8*)&s_lds[buf][row * 64 + ((sg ^ (row & 7)) << 3)] = (short8){0,0,0,0,0,0,0,0};
  }
  for (int i = tid; i < H_ * F_; i += 512) wout_lds[i] = W_out[i];

  // A-fragments register-resident for all 24 steps (lane: gate=base+l15, k=lhi*8)
  short8 whf[3][4];
  short8 mif[3][2];
  const float* whh_n = W_hh + (size_t)n * G3 * H_;
  const unsigned short* mi_n = Mi + (size_t)n * G3 * 64;
  #pragma unroll
  for (int ntl = 0; ntl < 3; ++ntl) {
    const int g = ntl * H_ + w * 16 + l15;
    #pragma unroll
    for (int ks = 0; ks < 4; ++ks) {
      const float4* p = (const float4*)(whh_n + (size_t)g * H_ + ks * 32 + lhi * 8);
      float4 a = p[0], b2 = p[1];
      short8 r;
      r[0]=(short)f2bf(a.x); r[1]=(short)f2bf(a.y); r[2]=(short)f2bf(a.z); r[3]=(short)f2bf(a.w);
      r[4]=(short)f2bf(b2.x); r[5]=(short)f2bf(b2.y); r[6]=(short)f2bf(b2.z); r[7]=(short)f2bf(b2.w);
      whf[ntl][ks] = r;
    }
    #pragma unroll
    for (int ks = 0; ks < 2; ++ks)
      mif[ntl][ks] = *(const short8*)(mi_n + (size_t)g * 64 + ks * 32 + lhi * 8);
  }

  // persistent bias C-registers: element r -> gate row j = w*16 + lhi*4 + r
  f32x4 cRZ0, cRZ1, cN, cHN, zero4 = {0.f, 0.f, 0.f, 0.f};
  {
    const float* bi = b_ih + n * G3;
    const float* bh = b_hh + n * G3;
    #pragma unroll
    for (int r = 0; r < 4; ++r) {
      int g0 = w * 16 + lhi * 4 + r;
      cRZ0[r] = bi[g0] + bh[g0];
      cRZ1[r] = bi[H_ + g0] + bh[H_ + g0];
      cN[r]   = bi[2 * H_ + g0];
      cHN[r]  = bh[2 * H_ + g0];
    }
  }

  // prologue: stage s[0] into buffer 0
  {
    short8 sv = {0,0,0,0,0,0,0,0};
    if (seg < 6) {
      const unsigned short* p;
      if (seg < 2)      p = xbf + (((size_t)brow * N_ + n) * W_ + 0) * 16 + seg * 8;
      else if (seg < 4) p = S1 + (size_t)n * XCOLS + (brow * W_ + 0) * 16 + (seg - 2) * 8;
      else              p = S2 + (size_t)n * XCOLS + (brow * W_ + 0) * 16 + (seg - 4) * 8;
      sv = *(const short8*)p;
      *(short8*)&s_lds[0][brow * 64 + ((seg ^ (brow & 7)) << 3)] = sv;
    }
  }
  __syncthreads();

  unsigned short* s_cur = s_lds[0]; unsigned short* s_nxt = s_lds[1];
  unsigned short* h_cur = h_lds[0]; unsigned short* h_nxt = h_lds[1];

  for (int t = 0; t < W_; ++t) {
    const bool do_stage = (t + 1 < W_) && (seg < 6);
    short8 sv;
    if (do_stage) {   // issue next-step loads early; latency hides under MFMA
      const unsigned short* p;
      if (seg < 2)      p = xbf + (((size_t)brow * N_ + n) * W_ + (t + 1)) * 16 + seg * 8;
      else if (seg < 4) p = S1 + (size_t)n * XCOLS + (brow * W_ + (t + 1)) * 16 + (seg - 2) * 8;
      else              p = S2 + (size_t)n * XCOLS + (brow * W_ + (t + 1)) * 16 + (seg - 4) * 8;
      sv = *(const short8*)p;
    }

    #pragma unroll 1
    for (int nt = 0; nt < 4; ++nt) {
      const int row = nt * 16 + l15;          // batch row (B-frag col & combine row)
      const int sw = (row & 7) << 3;
      const unsigned short* sr = &s_cur[row * 64];
      const unsigned short* hr = &h_cur[row * H_];
      short8 bs0 = *(const short8*)&sr[((0 * 4 + lhi) << 3) ^ sw];
      short8 bs1 = *(const short8*)&sr[((1 * 4 + lhi) << 3) ^ sw];
      short8 bh0 = *(const short8*)&hr[((0 * 4 + lhi) << 3) ^ sw];
      short8 bh1 = *(const short8*)&hr[((1 * 4 + lhi) << 3) ^ sw];
      short8 bh2 = *(const short8*)&hr[((2 * 4 + lhi) << 3) ^ sw];
      short8 bh3 = *(const short8*)&hr[((3 * 4 + lhi) << 3) ^ sw];

      f32x4 aI0 = MFMA(mif[0][0], bs0, cRZ0, 0, 0, 0);
      f32x4 aI1 = MFMA(mif[1][0], bs0, cRZ1, 0, 0, 0);
      f32x4 aI2 = MFMA(mif[2][0], bs0, cN,   0, 0, 0);
      aI0 = MFMA(mif[0][1], bs1, aI0, 0, 0, 0);
      aI1 = MFMA(mif[1][1], bs1, aI1, 0, 0, 0);
      aI2 = MFMA(mif[2][1], bs1, aI2, 0, 0, 0);
      f32x4 aH0 = MFMA(whf[0][0], bh0, zero4, 0, 0, 0);
      f32x4 aH1 = MFMA(whf[1][0], bh0, zero4, 0, 0, 0);
      f32x4 aH2 = MFMA(whf[2][0], bh0, cHN,   0, 0, 0);
      aH0 = MFMA(whf[0][1], bh1, aH0, 0, 0, 0);
      aH1 = MFMA(whf[1][1], bh1, aH1, 0, 0, 0);
      aH2 = MFMA(whf[2][1], bh1, aH2, 0, 0, 0);
      aH0 = MFMA(whf[0][2], bh2, aH0, 0, 0, 0);
      aH1 = MFMA(whf[1][2], bh2, aH1, 0, 0, 0);
      aH2 = MFMA(whf[2][2], bh2, aH2, 0, 0, 0);
      aH0 = MFMA(whf[0][3], bh3, aH0, 0, 0, 0);
      aH1 = MFMA(whf[1][3], bh3, aH1, 0, 0, 0);
      aH2 = MFMA(whf[2][3], bh3, aH2, 0, 0, 0);

      // combine (lane-local): j = w*16 + lhi*4 + r, batch = row; packed h I/O
      const int hpo = row * H_ + ((((w << 1) | (lhi >> 1)) << 3) ^ sw) + ((lhi & 1) << 2);
      ushort4 hp4 = *(const ushort4*)&h_cur[hpo];
      ushort4 hn4;
      #pragma unroll
      for (int r = 0; r < 4; ++r) {
        float rg = 1.f / (1.f + __expf(-(aI0[r] + aH0[r])));
        float zg = 1.f / (1.f + __expf(-(aI1[r] + aH1[r])));
        float tt = aI2[r] + rg * aH2[r];
        float e2 = __expf(-2.f * fabsf(tt));
        float th = copysignf((1.f - e2) / (1.f + e2), tt);
        float hp = bf2f(r == 0 ? hp4.x : r == 1 ? hp4.y : r == 2 ? hp4.z : hp4.w);
        float hv = th + zg * (hp - th);
        unsigned short hb = f2bf(hv);
        if (r == 0) hn4.x = hb; else if (r == 1) hn4.y = hb;
        else if (r == 2) hn4.z = hb; else hn4.w = hb;
      }
      *(ushort4*)&h_nxt[hpo] = hn4;
    }

    if (do_stage)
      *(short8*)&s_nxt[brow * 64 + ((seg ^ (brow & 7)) << 3)] = sv;
    __syncthreads();
    unsigned short* tp;
    tp = s_cur; s_cur = s_nxt; s_nxt = tp;
    tp = h_cur; h_cur = h_nxt; h_nxt = tp;
  }

  // epilogue: out[b][n][f] = h . W_out[:,f] + b_out[f]   (h in h_cur, swizzled)
  for (int e = tid; e < B_ * F_; e += 512) {
    const int b = e >> 4, f = e & 15;
    float acc = b_out[f];
    for (int js = 0; js < 16; ++js) {
      const int base = b * H_ + ((js ^ (b & 7)) << 3);
      #pragma unroll
      for (int i = 0; i < 8; ++i)
        acc += bf2f(h_cur[base + i]) * wout_lds[(js * 8 + i) * F_ + f];
    }
    out[((size_t)b * N_ + n) * F_ + f] = acc;
  }
}

extern "C" void kernel_launch(void* const* d_in, const int* in_sizes, int n_in,
                              void* d_out, int out_size, void* d_ws, size_t ws_size,
                              hipStream_t stream) {
  const float* x     = (const float*)d_in[0];
  const float* A_fw  = (const float*)d_in[1];
  const float* dc    = (const float*)d_in[2];
  const float* W_ih  = (const float*)d_in[3];
  const float* W_hh  = (const float*)d_in[4];
  const float* b_ih  = (const float*)d_in[5];
  const float* b_hh  = (const float*)d_in[6];
  const float* W_out = (const float*)d_in[7];
  const float* b_out = (const float*)d_in[8];
  float* out = (float*)d_out;

  // workspace (~101 MB)
  unsigned short* xbf = (unsigned short*)d_ws;             // 12.58M bf16
  unsigned short* S1  = xbf + (size_t)B_ * N_ * W_ * F_;
  unsigned short* S2  = S1 + (size_t)N_ * XCOLS;
  unsigned short* Mi  = S2 + (size_t)N_ * XCOLS;           // 512*384*64
  float* dcw = (float*)(Mi + (size_t)N_ * G3 * 64);
  float* val = dcw + 48 * H_;
  int*   idx = (int*)(val + N_ * CAP);
  int*   cnt = idx + N_ * CAP;

  xbf_conv<<<dim3(6144), dim3(256), 0, stream>>>(x, xbf);
  csr_build<<<dim3(N_), dim3(64), 0, stream>>>(A_fw, idx, val, cnt);
  dcw_build<<<dim3(1), dim3(256), 0, stream>>>(dc, dcw);
  dim3 gs(XCOLS4 / 256, N_);
  spmm_x<<<gs, dim3(256), 0, stream>>>(xbf, idx, val, cnt, S1);
  spmm_s<<<gs, dim3(256), 0, stream>>>(S1, idx, val, cnt, S2);
  prep_mi<<<dim3(N_), dim3(384), 0, stream>>>(dcw, W_ih, Mi);
  gru_mfma<<<dim3(N_), dim3(512), 0, stream>>>(xbf, S1, S2, Mi, W_hh, b_ih, b_hh,
                                               W_out, b_out, out);
}